// Round 5
// baseline (298.036 us; speedup 1.0000x reference)
//
#include <hip/hip_runtime.h>
#include <hip/hip_bf16.h>
#include <math.h>

typedef __hip_bfloat16 bf16;

// dtype: inputs are f32 (measured round 3), but keep runtime detect via the
// first 32-bit word of a ones-vector: f32 -> 0x3F800000, bf16 -> 0x3F803F80.
__device__ __forceinline__ bool detect_bf16(const void* ones_vec) {
  return ((const unsigned int*)ones_vec)[0] == 0x3F803F80u;
}
__device__ __forceinline__ float ldf(const void* p, long idx, bool isb) {
  if (isb) return __bfloat162float(((const bf16*)p)[idx]);
  return ((const float*)p)[idx];
}
__device__ __forceinline__ void stf(void* p, long idx, float v, bool isb) {
  if (isb) ((bf16*)p)[idx] = __float2bfloat16(v);
  else     ((float*)p)[idx] = v;
}
// butterfly sum across the full 64-lane wave
__device__ __forceinline__ float wsum64(float x) {
#pragma unroll
  for (int off = 32; off > 0; off >>= 1) x += __shfl_xor(x, off, 64);
  return x;
}
// butterfly sum within each 32-lane half
__device__ __forceinline__ float wsum32(float x) {
#pragma unroll
  for (int off = 16; off > 0; off >>= 1) x += __shfl_xor(x, off, 64);
  return x;
}

#define NREP 16   // accumulator replicas (atomic-contention dilution)

// ---------------------------------------------------------------------------
// Kernel 1 (fused): per-node pipeline + top-64 NN selection for residue i.
// Only change this round: zero NREP replicas of agg/v_agg.
// grid 512, block 256.
// ---------------------------------------------------------------------------
__global__ __launch_bounds__(256) void k_node_topk(
    const void* __restrict__ xyz, const void* __restrict__ state,
    const void* __restrict__ msa, const void* __restrict__ seq1hot,
    const void* __restrict__ g_msa, const void* __restrict__ b_msa,
    const void* __restrict__ g_state, const void* __restrict__ b_state,
    const void* __restrict__ g_node, const void* __restrict__ b_node,
    const void* __restrict__ Wx, const void* __restrict__ bx,
    const void* __restrict__ Wvv,
    float* __restrict__ l0, float* __restrict__ CA, float* __restrict__ v,
    float* __restrict__ vproj, float* __restrict__ agg, float* __restrict__ v_agg,
    int* __restrict__ nbr)
{
  const bool isb = detect_bf16(g_msa);
  const int i = blockIdx.x;
  const int t = threadIdx.x;
  const int lane = t & 63, w = t >> 6;
  __shared__ float nin[312];
  __shared__ float wred[2][4];
  __shared__ float part[8][32];
  __shared__ float sxyz[9], sv9[9];
  __shared__ float cx[512], cy[512], cz[512];
  __shared__ unsigned long long key[512];

  // ---- stage all CAs from xyz (for topk; independent of node pipeline) ----
  for (int tt = t; tt < 512; tt += 256) {
    cx[tt] = ldf(xyz, tt * 9 + 3, isb);
    cy[tt] = ldf(xyz, tt * 9 + 4, isb);
    cz[tt] = ldf(xyz, tt * 9 + 5, isb);
  }

  // ---- msa LN (256): one element per thread ----
  float x = ldf(msa, i * 256 + t, isb);
  float s1 = wsum64(x), s2 = wsum64(x * x);
  if (lane == 0) { wred[0][w] = s1; wred[1][w] = s2; }
  if (t < 9) sxyz[t] = ldf(xyz, i * 9 + t, isb);
  __syncthreads();
  float S  = wred[0][0] + wred[0][1] + wred[0][2] + wred[0][3];
  float Sq = wred[1][0] + wred[1][1] + wred[1][2] + wred[1][3];
  float mu = S * (1.f / 256.f);
  float rs = rsqrtf(fmaxf(Sq * (1.f / 256.f) - mu * mu, 0.f) + 1e-5f);
  nin[t] = (x - mu) * rs * ldf(g_msa, t, isb) + ldf(b_msa, t, isb);
  if (t < 21) nin[256 + t] = ldf(seq1hot, i * 21 + t, isb);
  if (t < 3)  nin[309 + t] = 0.f;

  // ---- state LN (32): wave 0 only ----
  if (w == 0) {
    float sx  = (lane < 32) ? ldf(state, i * 32 + lane, isb) : 0.f;
    float Ss  = wsum64(sx), Ssq = wsum64(sx * sx);
    float mus = Ss * (1.f / 32.f);
    float rss = rsqrtf(fmaxf(Ssq * (1.f / 32.f) - mus * mus, 0.f) + 1e-5f);
    if (lane < 32)
      nin[277 + lane] = (sx - mus) * rss * ldf(g_state, lane, isb) + ldf(b_state, lane, isb);
  }
  __syncthreads();

  // ---- Wx GEMV: thread (c, g) handles rows f ≡ g (mod 8) ----
  const int c = t & 31, g = t >> 5;
  float acc = 0.f;
  for (int f = g; f < 309; f += 8) acc += nin[f] * ldf(Wx, f * 32 + c, isb);
  part[g][c] = acc;

  // ---- topk: distances + packed keys (cx ready since barrier 1) ----
  float xi = cx[i], yi = cy[i], zi = cz[i];
  for (int tt = t; tt < 512; tt += 256) {
    float dx = cx[tt] - xi, dy = cy[tt] - yi, dz = cz[tt] - zi;
    float d2 = dx * dx + dy * dy + dz * dz;
    unsigned int bits = (tt == i) ? 0x7f800000u : __float_as_uint(d2);  // diag -> +inf
    key[tt] = ((unsigned long long)bits << 32) | (unsigned int)tt;
  }
  __syncthreads();

  if (w == 0) {
    float a = 0.f;
    if (lane < 32) {
      a = ldf(bx, lane, isb);
#pragma unroll
      for (int gg = 0; gg < 8; ++gg) a += part[gg][lane];
    }
    float Sa = wsum32(a), Saq = wsum32(a * a);   // payload only in lanes 0..31
    float mn = Sa * (1.f / 32.f);
    float rn = rsqrtf(fmaxf(Saq * (1.f / 32.f) - mn * mn, 0.f) + 1e-5f);
    if (lane < 32)
      l0[i * 32 + lane] = (a - mn) * rn * ldf(g_node, lane, isb) + ldf(b_node, lane, isb);
  } else if (w == 1) {
    if (lane < 3) CA[i * 3 + lane] = sxyz[3 + lane];
    if (lane < 9) {
      float vv = sxyz[lane] - sxyz[3 + lane % 3];
      v[i * 9 + lane] = vv;
      sv9[lane] = vv;
    }
  }
  // ---- zero NREP accumulator replicas for node i (no intra-kernel reader) ----
  for (int idx = t; idx < NREP * 32; idx += 256)
    agg[(idx >> 5) * (512 * 32) + i * 32 + (idx & 31)] = 0.f;
  if (t < NREP * 9)
    v_agg[(t / 9) * (512 * 9) + i * 9 + (t % 9)] = 0.f;
  __syncthreads();
  if (w == 1 && lane < 9) {
    int o = lane / 3, xc = lane % 3;
    float s = 0.f;
#pragma unroll
    for (int ii = 0; ii < 3; ++ii) s += ldf(Wvv, ii * 3 + o, isb) * sv9[ii * 3 + xc];
    vproj[i * 9 + lane] = s;
  }

  // ---- bitonic sort of 512 keys; lowest 64 -> nbr ----
  for (int k = 2; k <= 512; k <<= 1) {
    for (int j = k >> 1; j > 0; j >>= 1) {
      __syncthreads();
      int tt  = threadIdx.x;
      int i0 = ((tt & ~(j - 1)) << 1) | (tt & (j - 1));
      int i1 = i0 | j;
      bool up = ((i0 & k) == 0);
      unsigned long long a = key[i0], b = key[i1];
      if ((a > b) == up) { key[i0] = b; key[i1] = a; }
    }
  }
  __syncthreads();
  if (threadIdx.x < 64)
    nbr[i * 64 + threadIdx.x] = (int)(key[threadIdx.x] & 0xffffffffu);
}

// ---------------------------------------------------------------------------
// Kernel 3 (v8): batched-phase edge kernel + REPLICATED accumulators.
// grid 2048 = (i, quarter), block 256, 16 edges per block.
// Ledger: v7 k_edge = 51.5us; compute phases ~8us, staging ~5us -> residual
// ~40us attributed to atomic contention (1M agg + 0.3M v_agg f32 atomics,
// ~64 colliding adds/address). v8 scatters into replica r = blockIdx&15
// (= (i&3)*4+qt -> a dst j's 64 in-edges spread ~4/replica) -> 16x less
// per-address serialization. k_out sums replicas.
// ---------------------------------------------------------------------------
__global__ __launch_bounds__(256) void k_edge(
    const void* __restrict__ pair,
    const void* __restrict__ g_pair, const void* __restrict__ b_pair,
    const void* __restrict__ We1, const void* __restrict__ be1,
    const void* __restrict__ g_e1, const void* __restrict__ b_e1,
    const void* __restrict__ W1, const void* __restrict__ b1,
    const void* __restrict__ Wv,
    const int* __restrict__ nbr,
    const float* __restrict__ l0, const float* __restrict__ CA,
    const float* __restrict__ v, const float* __restrict__ vproj,
    float* __restrict__ agg, float* __restrict__ v_agg)
{
  const bool isb = detect_bf16(g_pair);
  __shared__ float WT[32][132];    // phase B: We1^T (k 0..127); phase D: W1 tail; col-rotated
  __shared__ float ped[16][132];   // normalized pair rows
  __shared__ float sinvL[16][68];  // [l0_j 0..31 | e1n 32..63 | dn 64 | sv 65..67]
  __shared__ float mL[16][33];
  __shared__ float coefL[16][8];
  __shared__ float geoE[16][4];    // dex,dey,dez
  __shared__ float gpl[128], bpl[128];
  __shared__ float a1b[32];        // b1 + l0_i @ W1[0:32]
  __shared__ float sgeo[21];       // CA_i[3], v_i[9], vproj_i[9]
  __shared__ float wvL[6][33];     // wvL[o][c] = Wv[c*6+o]
  __shared__ int   jnL[16];

  const int i  = blockIdx.x >> 2;
  const int qt = blockIdx.x & 3;
  const int rrep = blockIdx.x & (NREP - 1);   // replica id
  const int t  = threadIdx.x;
  const int e  = t >> 4;        // edge 0..15 (16 threads per edge)
  const int q  = t & 15;        // slice within row: elements [q*8, q*8+8)
  const int c  = t & 31;        // output column
  const int rg = t >> 5;        // row-group 0..7 -> rows 2rg, 2rg+1

  if (t < 16) jnL[t] = nbr[i * 64 + qt * 16 + t];
  __syncthreads();                                   // B1: jnL ready

  // ---- pair slice load (8 elems) — earliest (HBM) ----
  const int j_e = jnL[e];
  float4 pA, pB;
  {
    const size_t base = ((size_t)(i * 512 + j_e)) * 128 + q * 8;
    if (isb) {
      pA.x = ldf(pair, base + 0, true); pA.y = ldf(pair, base + 1, true);
      pA.z = ldf(pair, base + 2, true); pA.w = ldf(pair, base + 3, true);
      pB.x = ldf(pair, base + 4, true); pB.y = ldf(pair, base + 5, true);
      pB.z = ldf(pair, base + 6, true); pB.w = ldf(pair, base + 7, true);
    } else {
      const float4* p4 = (const float4*)pair;
      pA = p4[base >> 2]; pB = p4[(base >> 2) + 1];
    }
  }

  // ---- concurrent staging (overlaps pair-load latency) ----
  if (t < 128) gpl[t] = ldf(g_pair, t, isb);
  else         bpl[t - 128] = ldf(b_pair, t - 128, isb);
  // WT <- We1 transposed + column-rotated: element (c,k) at slot ((k>>2)+4*(c&7))&31
  for (int idx = t; idx < 4096; idx += 256) {
    int cc = idx & 31, k = idx >> 5;
    int slot = ((k >> 2) + 4 * (cc & 7)) & 31;
    WT[cc][slot * 4 + (k & 3)] = ldf(We1, idx, isb);
  }
  // l0_j -> sinvL[e][0..31] (2 elems/thread)
  {
    int ee = t >> 4, kk = (t & 15) * 2;
    const float2 lj = *(const float2*)&l0[jnL[ee] * 32 + kk];
    sinvL[ee][kk] = lj.x; sinvL[ee][kk + 1] = lj.y;
  }
  if (t < 3)       sgeo[t] = CA[i * 3 + t];
  else if (t < 12) sgeo[t] = v[i * 9 + (t - 3)];
  else if (t < 21) sgeo[t] = vproj[i * 9 + (t - 12)];
  if (t < 192) wvL[t % 6][t / 6] = ldf(Wv, t, isb);
  if (t < 32) {   // a1_base = b1[c] + l0_i @ W1[0:32,c]  (loop-invariant hoist)
    float b = ldf(b1, t, isb);
    for (int f = 0; f < 32; ++f) b += l0[i * 32 + f] * ldf(W1, f * 32 + t, isb);
    a1b[t] = b;
  }

  // ---- row LN stats: 16-lane butterfly over 8-elem partials ----
  float S  = pA.x + pA.y + pA.z + pA.w + pB.x + pB.y + pB.z + pB.w;
  float Sq = pA.x * pA.x + pA.y * pA.y + pA.z * pA.z + pA.w * pA.w
           + pB.x * pB.x + pB.y * pB.y + pB.z * pB.z + pB.w * pB.w;
#pragma unroll
  for (int off = 8; off > 0; off >>= 1) {
    S  += __shfl_xor(S,  off, 64);
    Sq += __shfl_xor(Sq, off, 64);
  }
  __syncthreads();                                   // B2: gpl/bpl, WT, sgeo, wvL, a1b, l0_j ready

  // ---- normalize slice -> ped ----
  {
    float mu = S * (1.f / 128.f);
    float rs = rsqrtf(fmaxf(Sq * (1.f / 128.f) - mu * mu, 0.f) + 1e-5f);
    float4 g0 = *(const float4*)&gpl[q * 8], g1 = *(const float4*)&gpl[q * 8 + 4];
    float4 b0 = *(const float4*)&bpl[q * 8], b1v = *(const float4*)&bpl[q * 8 + 4];
    float4 o0, o1;
    o0.x = (pA.x - mu) * rs * g0.x + b0.x;
    o0.y = (pA.y - mu) * rs * g0.y + b0.y;
    o0.z = (pA.z - mu) * rs * g0.z + b0.z;
    o0.w = (pA.w - mu) * rs * g0.w + b0.w;
    o1.x = (pB.x - mu) * rs * g1.x + b1v.x;
    o1.y = (pB.y - mu) * rs * g1.y + b1v.y;
    o1.z = (pB.z - mu) * rs * g1.z + b1v.z;
    o1.w = (pB.w - mu) * rs * g1.w + b1v.w;
    *(float4*)&ped[e][q * 8]     = o0;
    *(float4*)&ped[e][q * 8 + 4] = o1;
  }
  // ---- geometry per edge (sgeo safe after B2) ----
  if (t < 16) {
    int j = jnL[t];
    float dex = CA[j * 3 + 0] - sgeo[0];
    float dey = CA[j * 3 + 1] - sgeo[1];
    float dez = CA[j * 3 + 2] - sgeo[2];
    float dn  = sqrtf(dex * dex + dey * dey + dez * dez);
    float idn = 1.f / (dn + 1e-8f);
    float dux = dex * idn, duy = dey * idn, duz = dez * idn;
    sinvL[t][64] = dn;
    sinvL[t][65] = sgeo[3] * dux + sgeo[4] * duy + sgeo[5] * duz;
    sinvL[t][66] = sgeo[6] * dux + sgeo[7] * duy + sgeo[8] * duz;
    sinvL[t][67] = sgeo[9] * dux + sgeo[10] * duy + sgeo[11] * duz;
    geoE[t][0] = dex; geoE[t][1] = dey; geoE[t][2] = dez;
  }
  __syncthreads();                                   // B3: ped, geometry ready

  // ---- phase B: e1 GEMM [16x128]@[128x32], thread = (c, rows 2rg,2rg+1) ----
  const int e0 = rg * 2, e1i = rg * 2 + 1;
  const int rot = 4 * (c & 7);
  float A0 = ldf(be1, c, isb), A1 = A0;
#pragma unroll 4
  for (int k4 = 0; k4 < 32; ++k4) {
    float4 wf = *(const float4*)&WT[c][((k4 + rot) & 31) << 2];
    float4 p0 = *(const float4*)&ped[e0][k4 << 2];
    float4 p1 = *(const float4*)&ped[e1i][k4 << 2];
    A0 += p0.x * wf.x + p0.y * wf.y + p0.z * wf.z + p0.w * wf.w;
    A1 += p1.x * wf.x + p1.y * wf.y + p1.z * wf.z + p1.w * wf.w;
  }
  // e1 LN per row (stats across c within each 32-lane half)
  {
    const float ge1c = ldf(g_e1, c, isb), bee1c = ldf(b_e1, c, isb);
    float S0 = wsum32(A0), Q0 = wsum32(A0 * A0);
    float S1 = wsum32(A1), Q1 = wsum32(A1 * A1);
    float mu0 = S0 * (1.f / 32.f);
    float r0  = rsqrtf(fmaxf(Q0 * (1.f / 32.f) - mu0 * mu0, 0.f) + 1e-5f);
    float mu1 = S1 * (1.f / 32.f);
    float r1  = rsqrtf(fmaxf(Q1 * (1.f / 32.f) - mu1 * mu1, 0.f) + 1e-5f);
    sinvL[e0][32 + c]  = (A0 - mu0) * r0 * ge1c + bee1c;
    sinvL[e1i][32 + c] = (A1 - mu1) * r1 * ge1c + bee1c;
  }
  __syncthreads();                                   // B4: WT reads done, e1n written

  // ---- re-stage WT with W1 rows 32..99 (inv[32:100] weights) ----
  for (int idx = t; idx < 2176; idx += 256) {        // 68*32
    int cc = idx & 31, k = idx >> 5;
    int slot = ((k >> 2) + 4 * (cc & 7)) & 31;
    WT[cc][slot * 4 + (k & 3)] = ldf(W1, (32 + k) * 32 + cc, isb);
  }
  __syncthreads();                                   // B5

  // ---- phase D: m = gelu(a1b + inv[32:100] @ W1tail) ----
  {
    float M0 = a1b[c], M1 = M0;
#pragma unroll 4
    for (int k4 = 0; k4 < 17; ++k4) {
      float4 wf = *(const float4*)&WT[c][((k4 + rot) & 31) << 2];
      float4 s0 = *(const float4*)&sinvL[e0][k4 << 2];
      float4 s1 = *(const float4*)&sinvL[e1i][k4 << 2];
      M0 += s0.x * wf.x + s0.y * wf.y + s0.z * wf.z + s0.w * wf.w;
      M1 += s1.x * wf.x + s1.y * wf.y + s1.z * wf.z + s1.w * wf.w;
    }
    float u0 = 0.7978845608028654f * (M0 + 0.044715f * M0 * M0 * M0);
    float g0 = 0.5f * M0 * (1.f + tanhf(u0));
    float u1 = 0.7978845608028654f * (M1 + 0.044715f * M1 * M1 * M1);
    float g1 = 0.5f * M1 * (1.f + tanhf(u1));
    mL[e0][c] = g0;  mL[e1i][c] = g1;
    atomicAdd(&agg[rrep * (512 * 32) + jnL[e0] * 32 + c], g0);
    atomicAdd(&agg[rrep * (512 * 32) + jnL[e1i] * 32 + c], g1);
  }
  __syncthreads();                                   // B6: mL ready

  // ---- phase E: coef = m @ Wv ----
  if (t < 96) {
    int ee = t / 6, o = t - ee * 6;
    float s = 0.f;
#pragma unroll 8
    for (int cc = 0; cc < 32; ++cc) s += mL[ee][cc] * wvL[o][cc];
    coefL[ee][o] = s;
  }
  __syncthreads();                                   // B7: coef ready
  if (t < 144) {
    int ee = t / 9, l = t - ee * 9, o = l / 3, x = l - o * 3;
    float val = coefL[ee][o] * geoE[ee][x] + coefL[ee][3 + o] * sgeo[12 + o * 3 + x];
    atomicAdd(&v_agg[rrep * (512 * 9) + jnL[ee] * 9 + l], val);
  }
}

// ---------------------------------------------------------------------------
// Kernel 4: output heads. grid 512, block 64. Sums NREP replicas at read.
// ---------------------------------------------------------------------------
__global__ __launch_bounds__(64) void k_out(
    const float* __restrict__ l0, const float* __restrict__ agg,
    const float* __restrict__ v, const float* __restrict__ v_agg,
    const float* __restrict__ CA,
    const void* __restrict__ W2, const void* __restrict__ b2,
    const void* __restrict__ Wself,
    const void* __restrict__ g_state, const void* __restrict__ b_state,
    const void* __restrict__ Wl, const void* __restrict__ bl,
    void* __restrict__ out)
{
  const bool isb = detect_bf16(g_state);
  const int l = blockIdx.x;
  const int lane = threadIdx.x;
  const int c = lane & 31, h = lane >> 5;
  __shared__ float scat[64], soff[9];
  if (lane < 32) {
    scat[lane] = l0[l * 32 + lane];
    float s = 0.f;
#pragma unroll
    for (int r = 0; r < NREP; ++r) s += agg[r * (512 * 32) + l * 32 + lane];
    scat[32 + lane] = s;
  }
  __syncthreads();

  // h_out = [l0, agg] @ W2 + b2 : lane (c,h), inner half each
  float acc = 0.f;
  {
    const int fb = h * 32;
    for (int f = 0; f < 32; ++f) acc += scat[fb + f] * ldf(W2, (fb + f) * 32 + c, isb);
  }
  acc += __shfl_xor(acc, 32, 64);
  acc += ldf(b2, c, isb);

  float mu = wsum32(acc) * (1.f / 32.f);
  float rs = rsqrtf(fmaxf(wsum32(acc * acc) * (1.f / 32.f) - mu * mu, 0.f) + 1e-5f);
  float hn = (acc - mu) * rs * ldf(g_state, c, isb) + ldf(b_state, c, isb);
  float pre = wsum32(hn * ldf(Wl, c, isb)) + ldf(bl, 0, isb);
  if (lane == 0) stf(out, 4608 + l, 1.f / (1.f + expf(-pre)), isb);

  if (lane < 9) {
    int o = lane / 3, xx = lane % 3;
    float s = 0.f;
#pragma unroll
    for (int r = 0; r < NREP; ++r) s += v_agg[r * (512 * 9) + l * 9 + lane];
#pragma unroll
    for (int ii = 0; ii < 3; ++ii) s += ldf(Wself, ii * 3 + o, isb) * v[l * 9 + ii * 3 + xx];
    soff[lane] = s;
  }
  __syncthreads();
  if (lane < 9) {
    int xx = lane % 3;
    float add = (l == 0) ? 0.f : (CA[l * 3 + xx] + soff[3 + xx]);  // residue 0 zeroed
    stf(out, l * 9 + lane, soff[lane] + add, isb);
  }
}

extern "C" void kernel_launch(void* const* d_in, const int* in_sizes, int n_in,
                              void* d_out, int out_size, void* d_ws, size_t ws_size,
                              hipStream_t stream) {
  (void)in_sizes; (void)n_in; (void)out_size; (void)ws_size;
  const void* xyz     = d_in[0];
  const void* state   = d_in[1];
  const void* msa     = d_in[4];
  const void* pair    = d_in[5];
  const void* seq1hot = d_in[6];
  const void* g_msa   = d_in[10];
  const void* b_msa   = d_in[11];
  const void* g_pair  = d_in[12];
  const void* b_pair  = d_in[13];
  const void* g_state = d_in[14];
  const void* b_state = d_in[15];
  const void* g_node  = d_in[16];
  const void* b_node  = d_in[17];
  const void* g_e1    = d_in[18];
  const void* b_e1    = d_in[19];
  const void* Wx      = d_in[20];
  const void* bx      = d_in[21];
  const void* We1     = d_in[22];
  const void* be1     = d_in[23];
  const void* W1      = d_in[24];
  const void* b1      = d_in[25];
  const void* W2      = d_in[26];
  const void* b2      = d_in[27];
  const void* Wv      = d_in[28];
  const void* Wvv     = d_in[29];
  const void* Wself   = d_in[30];
  const void* Wl      = d_in[31];
  const void* bl      = d_in[32];

  float* ws    = (float*)d_ws;
  float* l0    = ws;            // 512*32
  float* CA    = ws + 16384;    // 512*3
  float* v     = ws + 17920;    // 512*9
  float* vproj = ws + 22528;    // 512*9
  int*   nbr   = (int*)(ws + 48128);  // 512*64 ints -> ends at float 80896
  float* aggR  = ws + 90112;    // NREP * 512*32 = 262144 floats
  float* vaggR = ws + 360448;   // NREP * 512*9  = 73728 floats

  hipLaunchKernelGGL(k_node_topk, dim3(512), dim3(256), 0, stream,
                     xyz, state, msa, seq1hot, g_msa, b_msa, g_state, b_state,
                     g_node, b_node, Wx, bx, Wvv, l0, CA, v, vproj, aggR, vaggR, nbr);
  hipLaunchKernelGGL(k_edge, dim3(2048), dim3(256), 0, stream,
                     pair, g_pair, b_pair, We1, be1, g_e1, b_e1, W1, b1, Wv,
                     nbr, l0, CA, v, vproj, aggR, vaggR);
  hipLaunchKernelGGL(k_out, dim3(512), dim3(64), 0, stream,
                     l0, aggR, v, vaggR, CA, W2, b2, Wself, g_state, b_state, Wl, bl,
                     (void*)d_out);
}

// Round 6
// 290.788 us; speedup vs baseline: 1.0249x; 1.0249x over previous
//
#include <hip/hip_runtime.h>
#include <hip/hip_bf16.h>
#include <math.h>

typedef __hip_bfloat16 bf16;

// dtype: inputs are f32 (measured round 3), but keep runtime detect via the
// first 32-bit word of a ones-vector: f32 -> 0x3F800000, bf16 -> 0x3F803F80.
__device__ __forceinline__ bool detect_bf16(const void* ones_vec) {
  return ((const unsigned int*)ones_vec)[0] == 0x3F803F80u;
}
__device__ __forceinline__ float ldf(const void* p, long idx, bool isb) {
  if (isb) return __bfloat162float(((const bf16*)p)[idx]);
  return ((const float*)p)[idx];
}
__device__ __forceinline__ void stf(void* p, long idx, float v, bool isb) {
  if (isb) ((bf16*)p)[idx] = __float2bfloat16(v);
  else     ((float*)p)[idx] = v;
}
// butterfly sum across the full 64-lane wave
__device__ __forceinline__ float wsum64(float x) {
#pragma unroll
  for (int off = 32; off > 0; off >>= 1) x += __shfl_xor(x, off, 64);
  return x;
}
// butterfly sum within each 32-lane half
__device__ __forceinline__ float wsum32(float x) {
#pragma unroll
  for (int off = 16; off > 0; off >>= 1) x += __shfl_xor(x, off, 64);
  return x;
}

// ---------------------------------------------------------------------------
// Kernel 1 (fused): per-node pipeline + top-64 NN selection for residue i.
// (v7 version restored: single agg/v_agg, zeroed here.)
// grid 512, block 256.
// ---------------------------------------------------------------------------
__global__ __launch_bounds__(256) void k_node_topk(
    const void* __restrict__ xyz, const void* __restrict__ state,
    const void* __restrict__ msa, const void* __restrict__ seq1hot,
    const void* __restrict__ g_msa, const void* __restrict__ b_msa,
    const void* __restrict__ g_state, const void* __restrict__ b_state,
    const void* __restrict__ g_node, const void* __restrict__ b_node,
    const void* __restrict__ Wx, const void* __restrict__ bx,
    const void* __restrict__ Wvv,
    float* __restrict__ l0, float* __restrict__ CA, float* __restrict__ v,
    float* __restrict__ vproj, float* __restrict__ agg, float* __restrict__ v_agg,
    int* __restrict__ nbr)
{
  const bool isb = detect_bf16(g_msa);
  const int i = blockIdx.x;
  const int t = threadIdx.x;
  const int lane = t & 63, w = t >> 6;
  __shared__ float nin[312];
  __shared__ float wred[2][4];
  __shared__ float part[8][32];
  __shared__ float sxyz[9], sv9[9];
  __shared__ float cx[512], cy[512], cz[512];
  __shared__ unsigned long long key[512];

  // ---- stage all CAs from xyz (for topk; independent of node pipeline) ----
  for (int tt = t; tt < 512; tt += 256) {
    cx[tt] = ldf(xyz, tt * 9 + 3, isb);
    cy[tt] = ldf(xyz, tt * 9 + 4, isb);
    cz[tt] = ldf(xyz, tt * 9 + 5, isb);
  }

  // ---- msa LN (256): one element per thread ----
  float x = ldf(msa, i * 256 + t, isb);
  float s1 = wsum64(x), s2 = wsum64(x * x);
  if (lane == 0) { wred[0][w] = s1; wred[1][w] = s2; }
  if (t < 9) sxyz[t] = ldf(xyz, i * 9 + t, isb);
  __syncthreads();
  float S  = wred[0][0] + wred[0][1] + wred[0][2] + wred[0][3];
  float Sq = wred[1][0] + wred[1][1] + wred[1][2] + wred[1][3];
  float mu = S * (1.f / 256.f);
  float rs = rsqrtf(fmaxf(Sq * (1.f / 256.f) - mu * mu, 0.f) + 1e-5f);
  nin[t] = (x - mu) * rs * ldf(g_msa, t, isb) + ldf(b_msa, t, isb);
  if (t < 21) nin[256 + t] = ldf(seq1hot, i * 21 + t, isb);
  if (t < 3)  nin[309 + t] = 0.f;

  // ---- state LN (32): wave 0 only ----
  if (w == 0) {
    float sx  = (lane < 32) ? ldf(state, i * 32 + lane, isb) : 0.f;
    float Ss  = wsum64(sx), Ssq = wsum64(sx * sx);
    float mus = Ss * (1.f / 32.f);
    float rss = rsqrtf(fmaxf(Ssq * (1.f / 32.f) - mus * mus, 0.f) + 1e-5f);
    if (lane < 32)
      nin[277 + lane] = (sx - mus) * rss * ldf(g_state, lane, isb) + ldf(b_state, lane, isb);
  }
  __syncthreads();

  // ---- Wx GEMV: thread (c, g) handles rows f ≡ g (mod 8) ----
  const int c = t & 31, g = t >> 5;
  float acc = 0.f;
  for (int f = g; f < 309; f += 8) acc += nin[f] * ldf(Wx, f * 32 + c, isb);
  part[g][c] = acc;

  // ---- topk: distances + packed keys (cx ready since barrier 1) ----
  float xi = cx[i], yi = cy[i], zi = cz[i];
  for (int tt = t; tt < 512; tt += 256) {
    float dx = cx[tt] - xi, dy = cy[tt] - yi, dz = cz[tt] - zi;
    float d2 = dx * dx + dy * dy + dz * dz;
    unsigned int bits = (tt == i) ? 0x7f800000u : __float_as_uint(d2);  // diag -> +inf
    key[tt] = ((unsigned long long)bits << 32) | (unsigned int)tt;
  }
  __syncthreads();

  if (w == 0) {
    float a = 0.f;
    if (lane < 32) {
      a = ldf(bx, lane, isb);
#pragma unroll
      for (int gg = 0; gg < 8; ++gg) a += part[gg][lane];
    }
    float Sa = wsum32(a), Saq = wsum32(a * a);   // payload only in lanes 0..31
    float mn = Sa * (1.f / 32.f);
    float rn = rsqrtf(fmaxf(Saq * (1.f / 32.f) - mn * mn, 0.f) + 1e-5f);
    if (lane < 32)
      l0[i * 32 + lane] = (a - mn) * rn * ldf(g_node, lane, isb) + ldf(b_node, lane, isb);
  } else if (w == 1) {
    if (lane < 3) CA[i * 3 + lane] = sxyz[3 + lane];
    if (lane < 9) {
      float vv = sxyz[lane] - sxyz[3 + lane % 3];
      v[i * 9 + lane] = vv;
      sv9[lane] = vv;
    }
    if (lane < 32) agg[i * 32 + lane] = 0.f;
  } else if (w == 2) {
    if (lane < 9) v_agg[i * 9 + lane] = 0.f;
  }
  __syncthreads();
  if (w == 1 && lane < 9) {
    int o = lane / 3, xc = lane % 3;
    float s = 0.f;
#pragma unroll
    for (int ii = 0; ii < 3; ++ii) s += ldf(Wvv, ii * 3 + o, isb) * sv9[ii * 3 + xc];
    vproj[i * 9 + lane] = s;
  }

  // ---- bitonic sort of 512 keys; lowest 64 -> nbr ----
  for (int k = 2; k <= 512; k <<= 1) {
    for (int j = k >> 1; j > 0; j >>= 1) {
      __syncthreads();
      int tt  = threadIdx.x;
      int i0 = ((tt & ~(j - 1)) << 1) | (tt & (j - 1));
      int i1 = i0 | j;
      bool up = ((i0 & k) == 0);
      unsigned long long a = key[i0], b = key[i1];
      if ((a > b) == up) { key[i0] = b; key[i1] = a; }
    }
  }
  __syncthreads();
  if (threadIdx.x < 64)
    nbr[i * 64 + threadIdx.x] = (int)(key[threadIdx.x] & 0xffffffffu);
}

// ---------------------------------------------------------------------------
// Kernel 3 (v9): batched-phase edge kernel, latency-trimmed.
// grid 2048 = (i, quarter), block 256, 16 edges per block.
// Post-mortem v8: 16x replica accumulators did NOT help (292 -> 298) =>
// atomic contention was never the residual; replication reverted.
// v9 = v7 + latency fixes:
//   * B1 barrier removed: each thread loads its own jn (wave-broadcast
//     line); q==0 threads publish jnL for post-B2 consumers.
//   * a1_base parallelized: 8x32 partials (4 pipelined loads/thread) into
//     LDS pre-B2, 32-thread reduce post-B2. Kills the 32-deep serial
//     global-load chain that sat on the critical path.
// ---------------------------------------------------------------------------
__global__ __launch_bounds__(256) void k_edge(
    const void* __restrict__ pair,
    const void* __restrict__ g_pair, const void* __restrict__ b_pair,
    const void* __restrict__ We1, const void* __restrict__ be1,
    const void* __restrict__ g_e1, const void* __restrict__ b_e1,
    const void* __restrict__ W1, const void* __restrict__ b1,
    const void* __restrict__ Wv,
    const int* __restrict__ nbr,
    const float* __restrict__ l0, const float* __restrict__ CA,
    const float* __restrict__ v, const float* __restrict__ vproj,
    float* __restrict__ agg, float* __restrict__ v_agg)
{
  const bool isb = detect_bf16(g_pair);
  __shared__ float WT[32][132];    // phase B: We1^T (k 0..127); phase D: W1 tail; col-rotated
  __shared__ float ped[16][132];   // normalized pair rows
  __shared__ float sinvL[16][68];  // [l0_j 0..31 | e1n 32..63 | dn 64 | sv 65..67]
  __shared__ float mL[16][33];
  __shared__ float coefL[16][8];
  __shared__ float geoE[16][4];    // dex,dey,dez
  __shared__ float gpl[128], bpl[128];
  __shared__ float partA[8][33];   // a1_base partials
  __shared__ float a1b[32];        // b1 + l0_i @ W1[0:32]
  __shared__ float sgeo[21];       // CA_i[3], v_i[9], vproj_i[9]
  __shared__ float wvL[6][33];     // wvL[o][c] = Wv[c*6+o]
  __shared__ int   jnL[16];

  const int i  = blockIdx.x >> 2;
  const int qt = blockIdx.x & 3;
  const int t  = threadIdx.x;
  const int e  = t >> 4;        // edge 0..15 (16 threads per edge)
  const int q  = t & 15;        // slice within row: elements [q*8, q*8+8)
  const int c  = t & 31;        // output column
  const int rg = t >> 5;        // row-group 0..7 -> rows 2rg, 2rg+1

  // ---- per-thread neighbor id (wave-broadcast line; no barrier needed) ----
  const int jn = nbr[i * 64 + qt * 16 + e];
  if (q == 0) jnL[e] = jn;      // for post-B2 consumers (geometry/scatter)

  // ---- pair slice load (8 elems) — earliest (HBM) ----
  float4 pA, pB;
  {
    const size_t base = ((size_t)(i * 512 + jn)) * 128 + q * 8;
    if (isb) {
      pA.x = ldf(pair, base + 0, true); pA.y = ldf(pair, base + 1, true);
      pA.z = ldf(pair, base + 2, true); pA.w = ldf(pair, base + 3, true);
      pB.x = ldf(pair, base + 4, true); pB.y = ldf(pair, base + 5, true);
      pB.z = ldf(pair, base + 6, true); pB.w = ldf(pair, base + 7, true);
    } else {
      const float4* p4 = (const float4*)pair;
      pA = p4[base >> 2]; pB = p4[(base >> 2) + 1];
    }
  }

  // ---- concurrent staging (overlaps pair-load latency) ----
  if (t < 128) gpl[t] = ldf(g_pair, t, isb);
  else         bpl[t - 128] = ldf(b_pair, t - 128, isb);
  // WT <- We1 transposed + column-rotated: element (c,k) at slot ((k>>2)+4*(c&7))&31
  for (int idx = t; idx < 4096; idx += 256) {
    int cc = idx & 31, k = idx >> 5;
    int slot = ((k >> 2) + 4 * (cc & 7)) & 31;
    WT[cc][slot * 4 + (k & 3)] = ldf(We1, idx, isb);
  }
  // l0_j -> sinvL[e][0..31] (2 elems/thread; own jn)
  {
    int kk = q * 2;
    const float2 lj = *(const float2*)&l0[jn * 32 + kk];
    sinvL[e][kk] = lj.x; sinvL[e][kk + 1] = lj.y;
  }
  if (t < 3)       sgeo[t] = CA[i * 3 + t];
  else if (t < 12) sgeo[t] = v[i * 9 + (t - 3)];
  else if (t < 21) sgeo[t] = vproj[i * 9 + (t - 12)];
  if (t < 192) wvL[t % 6][t / 6] = ldf(Wv, t, isb);
  // a1_base partials: thread (c, fg) covers f = 4*fg .. 4*fg+3 (pipelined loads)
  {
    const int fg = t >> 5;
    float p = 0.f;
#pragma unroll
    for (int k = 0; k < 4; ++k) {
      int f = 4 * fg + k;
      p += l0[i * 32 + f] * ldf(W1, f * 32 + c, isb);
    }
    partA[fg][c] = p;
  }

  // ---- row LN stats: 16-lane butterfly over 8-elem partials ----
  float S  = pA.x + pA.y + pA.z + pA.w + pB.x + pB.y + pB.z + pB.w;
  float Sq = pA.x * pA.x + pA.y * pA.y + pA.z * pA.z + pA.w * pA.w
           + pB.x * pB.x + pB.y * pB.y + pB.z * pB.z + pB.w * pB.w;
#pragma unroll
  for (int off = 8; off > 0; off >>= 1) {
    S  += __shfl_xor(S,  off, 64);
    Sq += __shfl_xor(Sq, off, 64);
  }
  __syncthreads();                                   // B2: staging + partials ready

  // ---- a1_base reduce (visible by B3 for phase D) ----
  if (t < 32) {
    float b = ldf(b1, t, isb);
#pragma unroll
    for (int gg = 0; gg < 8; ++gg) b += partA[gg][t];
    a1b[t] = b;
  }

  // ---- normalize slice -> ped ----
  {
    float mu = S * (1.f / 128.f);
    float rs = rsqrtf(fmaxf(Sq * (1.f / 128.f) - mu * mu, 0.f) + 1e-5f);
    float4 g0 = *(const float4*)&gpl[q * 8], g1 = *(const float4*)&gpl[q * 8 + 4];
    float4 b0 = *(const float4*)&bpl[q * 8], b1v = *(const float4*)&bpl[q * 8 + 4];
    float4 o0, o1;
    o0.x = (pA.x - mu) * rs * g0.x + b0.x;
    o0.y = (pA.y - mu) * rs * g0.y + b0.y;
    o0.z = (pA.z - mu) * rs * g0.z + b0.z;
    o0.w = (pA.w - mu) * rs * g0.w + b0.w;
    o1.x = (pB.x - mu) * rs * g1.x + b1v.x;
    o1.y = (pB.y - mu) * rs * g1.y + b1v.y;
    o1.z = (pB.z - mu) * rs * g1.z + b1v.z;
    o1.w = (pB.w - mu) * rs * g1.w + b1v.w;
    *(float4*)&ped[e][q * 8]     = o0;
    *(float4*)&ped[e][q * 8 + 4] = o1;
  }
  // ---- geometry per edge (sgeo + jnL safe after B2) ----
  if (t < 16) {
    int j = jnL[t];
    float dex = CA[j * 3 + 0] - sgeo[0];
    float dey = CA[j * 3 + 1] - sgeo[1];
    float dez = CA[j * 3 + 2] - sgeo[2];
    float dn  = sqrtf(dex * dex + dey * dey + dez * dez);
    float idn = 1.f / (dn + 1e-8f);
    float dux = dex * idn, duy = dey * idn, duz = dez * idn;
    sinvL[t][64] = dn;
    sinvL[t][65] = sgeo[3] * dux + sgeo[4] * duy + sgeo[5] * duz;
    sinvL[t][66] = sgeo[6] * dux + sgeo[7] * duy + sgeo[8] * duz;
    sinvL[t][67] = sgeo[9] * dux + sgeo[10] * duy + sgeo[11] * duz;
    geoE[t][0] = dex; geoE[t][1] = dey; geoE[t][2] = dez;
  }
  __syncthreads();                                   // B3: ped, geometry, a1b ready

  // ---- phase B: e1 GEMM [16x128]@[128x32], thread = (c, rows 2rg,2rg+1) ----
  const int e0 = rg * 2, e1i = rg * 2 + 1;
  const int rot = 4 * (c & 7);
  float A0 = ldf(be1, c, isb), A1 = A0;
#pragma unroll 4
  for (int k4 = 0; k4 < 32; ++k4) {
    float4 wf = *(const float4*)&WT[c][((k4 + rot) & 31) << 2];
    float4 p0 = *(const float4*)&ped[e0][k4 << 2];
    float4 p1 = *(const float4*)&ped[e1i][k4 << 2];
    A0 += p0.x * wf.x + p0.y * wf.y + p0.z * wf.z + p0.w * wf.w;
    A1 += p1.x * wf.x + p1.y * wf.y + p1.z * wf.z + p1.w * wf.w;
  }
  // e1 LN per row (stats across c within each 32-lane half)
  {
    const float ge1c = ldf(g_e1, c, isb), bee1c = ldf(b_e1, c, isb);
    float S0 = wsum32(A0), Q0 = wsum32(A0 * A0);
    float S1 = wsum32(A1), Q1 = wsum32(A1 * A1);
    float mu0 = S0 * (1.f / 32.f);
    float r0  = rsqrtf(fmaxf(Q0 * (1.f / 32.f) - mu0 * mu0, 0.f) + 1e-5f);
    float mu1 = S1 * (1.f / 32.f);
    float r1  = rsqrtf(fmaxf(Q1 * (1.f / 32.f) - mu1 * mu1, 0.f) + 1e-5f);
    sinvL[e0][32 + c]  = (A0 - mu0) * r0 * ge1c + bee1c;
    sinvL[e1i][32 + c] = (A1 - mu1) * r1 * ge1c + bee1c;
  }
  __syncthreads();                                   // B4: WT reads done, e1n written

  // ---- re-stage WT with W1 rows 32..99 (inv[32:100] weights) ----
  for (int idx = t; idx < 2176; idx += 256) {        // 68*32
    int cc = idx & 31, k = idx >> 5;
    int slot = ((k >> 2) + 4 * (cc & 7)) & 31;
    WT[cc][slot * 4 + (k & 3)] = ldf(W1, (32 + k) * 32 + cc, isb);
  }
  __syncthreads();                                   // B5

  // ---- phase D: m = gelu(a1b + inv[32:100] @ W1tail) ----
  {
    float M0 = a1b[c], M1 = M0;
#pragma unroll 4
    for (int k4 = 0; k4 < 17; ++k4) {
      float4 wf = *(const float4*)&WT[c][((k4 + rot) & 31) << 2];
      float4 s0 = *(const float4*)&sinvL[e0][k4 << 2];
      float4 s1 = *(const float4*)&sinvL[e1i][k4 << 2];
      M0 += s0.x * wf.x + s0.y * wf.y + s0.z * wf.z + s0.w * wf.w;
      M1 += s1.x * wf.x + s1.y * wf.y + s1.z * wf.z + s1.w * wf.w;
    }
    float u0 = 0.7978845608028654f * (M0 + 0.044715f * M0 * M0 * M0);
    float g0 = 0.5f * M0 * (1.f + tanhf(u0));
    float u1 = 0.7978845608028654f * (M1 + 0.044715f * M1 * M1 * M1);
    float g1 = 0.5f * M1 * (1.f + tanhf(u1));
    mL[e0][c] = g0;  mL[e1i][c] = g1;
    atomicAdd(&agg[jnL[e0] * 32 + c], g0);
    atomicAdd(&agg[jnL[e1i] * 32 + c], g1);
  }
  __syncthreads();                                   // B6: mL ready

  // ---- phase E: coef = m @ Wv ----
  if (t < 96) {
    int ee = t / 6, o = t - ee * 6;
    float s = 0.f;
#pragma unroll 8
    for (int cc = 0; cc < 32; ++cc) s += mL[ee][cc] * wvL[o][cc];
    coefL[ee][o] = s;
  }
  __syncthreads();                                   // B7: coef ready
  if (t < 144) {
    int ee = t / 9, l = t - ee * 9, o = l / 3, x = l - o * 3;
    float val = coefL[ee][o] * geoE[ee][x] + coefL[ee][3 + o] * sgeo[12 + o * 3 + x];
    atomicAdd(&v_agg[jnL[ee] * 9 + l], val);
  }
}

// ---------------------------------------------------------------------------
// Kernel 4: output heads. grid 512, block 64. (v7 version restored)
// ---------------------------------------------------------------------------
__global__ __launch_bounds__(64) void k_out(
    const float* __restrict__ l0, const float* __restrict__ agg,
    const float* __restrict__ v, const float* __restrict__ v_agg,
    const float* __restrict__ CA,
    const void* __restrict__ W2, const void* __restrict__ b2,
    const void* __restrict__ Wself,
    const void* __restrict__ g_state, const void* __restrict__ b_state,
    const void* __restrict__ Wl, const void* __restrict__ bl,
    void* __restrict__ out)
{
  const bool isb = detect_bf16(g_state);
  const int l = blockIdx.x;
  const int lane = threadIdx.x;
  const int c = lane & 31, h = lane >> 5;
  __shared__ float scat[64], soff[9];
  if (lane < 32) { scat[lane] = l0[l * 32 + lane]; scat[32 + lane] = agg[l * 32 + lane]; }
  __syncthreads();

  // h_out = [l0, agg] @ W2 + b2 : lane (c,h), inner half each
  float acc = 0.f;
  {
    const int fb = h * 32;
    for (int f = 0; f < 32; ++f) acc += scat[fb + f] * ldf(W2, (fb + f) * 32 + c, isb);
  }
  acc += __shfl_xor(acc, 32, 64);
  acc += ldf(b2, c, isb);

  float mu = wsum32(acc) * (1.f / 32.f);
  float rs = rsqrtf(fmaxf(wsum32(acc * acc) * (1.f / 32.f) - mu * mu, 0.f) + 1e-5f);
  float hn = (acc - mu) * rs * ldf(g_state, c, isb) + ldf(b_state, c, isb);
  float pre = wsum32(hn * ldf(Wl, c, isb)) + ldf(bl, 0, isb);
  if (lane == 0) stf(out, 4608 + l, 1.f / (1.f + expf(-pre)), isb);

  if (lane < 9) {
    int o = lane / 3, xx = lane % 3;
    float s = v_agg[l * 9 + lane];
#pragma unroll
    for (int ii = 0; ii < 3; ++ii) s += ldf(Wself, ii * 3 + o, isb) * v[l * 9 + ii * 3 + xx];
    soff[lane] = s;
  }
  __syncthreads();
  if (lane < 9) {
    int xx = lane % 3;
    float add = (l == 0) ? 0.f : (CA[l * 3 + xx] + soff[3 + xx]);  // residue 0 zeroed
    stf(out, l * 9 + lane, soff[lane] + add, isb);
  }
}

extern "C" void kernel_launch(void* const* d_in, const int* in_sizes, int n_in,
                              void* d_out, int out_size, void* d_ws, size_t ws_size,
                              hipStream_t stream) {
  (void)in_sizes; (void)n_in; (void)out_size; (void)ws_size;
  const void* xyz     = d_in[0];
  const void* state   = d_in[1];
  const void* msa     = d_in[4];
  const void* pair    = d_in[5];
  const void* seq1hot = d_in[6];
  const void* g_msa   = d_in[10];
  const void* b_msa   = d_in[11];
  const void* g_pair  = d_in[12];
  const void* b_pair  = d_in[13];
  const void* g_state = d_in[14];
  const void* b_state = d_in[15];
  const void* g_node  = d_in[16];
  const void* b_node  = d_in[17];
  const void* g_e1    = d_in[18];
  const void* b_e1    = d_in[19];
  const void* Wx      = d_in[20];
  const void* bx      = d_in[21];
  const void* We1     = d_in[22];
  const void* be1     = d_in[23];
  const void* W1      = d_in[24];
  const void* b1      = d_in[25];
  const void* W2      = d_in[26];
  const void* b2      = d_in[27];
  const void* Wv      = d_in[28];
  const void* Wvv     = d_in[29];
  const void* Wself   = d_in[30];
  const void* Wl      = d_in[31];
  const void* bl      = d_in[32];

  float* ws    = (float*)d_ws;
  float* l0    = ws;            // 512*32
  float* CA    = ws + 16384;    // 512*3
  float* v     = ws + 17920;    // 512*9
  float* vproj = ws + 22528;    // 512*9
  float* agg   = ws + 27136;    // 512*32
  float* v_agg = ws + 43520;    // 512*9
  int*   nbr   = (int*)(ws + 48128);  // 512*64 ints

  hipLaunchKernelGGL(k_node_topk, dim3(512), dim3(256), 0, stream,
                     xyz, state, msa, seq1hot, g_msa, b_msa, g_state, b_state,
                     g_node, b_node, Wx, bx, Wvv, l0, CA, v, vproj, agg, v_agg, nbr);
  hipLaunchKernelGGL(k_edge, dim3(2048), dim3(256), 0, stream,
                     pair, g_pair, b_pair, We1, be1, g_e1, b_e1, W1, b1, Wv,
                     nbr, l0, CA, v, vproj, agg, v_agg);
  hipLaunchKernelGGL(k_out, dim3(512), dim3(64), 0, stream,
                     l0, agg, v, v_agg, CA, W2, b2, Wself, g_state, b_state, Wl, bl,
                     (void*)d_out);
}